// Round 9
// baseline (292.760 us; speedup 1.0000x reference)
//
#include <hip/hip_runtime.h>
#include <hip/hip_bf16.h>
#include <math.h>

#define NEXP 64
#define TOPK 8
#define WPB 4                   // waves per block (fully independent, no barriers)
#define RPW 64                  // rows per wave
#define CPP 4                   // float4 chunks per phase
#define NPH 4                   // phases; CPP*NPH = 16 chunks = 64 floats/row

typedef float floatx4 __attribute__((ext_vector_type(4)));   // native vec for nontemporal builtins

// 4 independent waves per block; each wave owns a private LDS quarter and
// 64 rows. No __syncthreads anywhere: LDS write->read ordering within one
// wave is program-order (per-wave in-order DS pipeline). launch_bounds
// (256,8) caps VGPR at 64 -> 8 waves/SIMD = 32 waves/CU (TLP replaces the
// register prefetch we removed).
__global__ __launch_bounds__(256, 8) void topk_router_kernel(
    const float* __restrict__ logits,
    float* __restrict__ w_out,      // [N,8] weights
    float* __restrict__ id_out,     // [N,8] ids stored as float values
    float* __restrict__ l_out,      // [N,64] passthrough copy
    int nrows)
{
    // per-wave tile: [c][r], c in 0..3, r in 0..63. Slot index = c*64+r;
    // slot mod 8 is uniform over the wave on both write (r-driven) and read
    // (lane-driven) side -> conflict-free for ds_*_b128 without swizzle.
    __shared__ float4 tile[WPB * CPP * RPW];   // 16 KB total

    const int lane = threadIdx.x & 63;
    const int w    = threadIdx.x >> 6;
    float4* __restrict__ wtile = &tile[w * (CPP * RPW)];

    const int rowBase = blockIdx.x * (WPB * RPW) + w * RPW;
    const size_t waveBase4 = (size_t)rowBase * (NEXP / 4);
    const size_t totalChunks = (size_t)nrows * (NEXP / 4);

    const float4* __restrict__ src = (const float4*)logits;
    float4* __restrict__ dst = (float4*)l_out;

    // ---- top-8 by logit (stable: strict >, increasing index) + max of
    // rejected (rm) for the 8/9-boundary tie screen ----
    float tv0 = -INFINITY, tv1 = -INFINITY, tv2 = -INFINITY, tv3 = -INFINITY;
    float tv4 = -INFINITY, tv5 = -INFINITY, tv6 = -INFINITY, tv7 = -INFINITY;
    float rm  = -INFINITY;
    int   ti0 = 0, ti1 = 0, ti2 = 0, ti3 = 0;
    int   ti4 = 0, ti5 = 0, ti6 = 0, ti7 = 0;

#define INSERT_STAGE(TV, TI)                              \
    {                                                     \
        bool gt = (x > TV);                               \
        float nv = gt ? x  : TV;                          \
        float cv = gt ? TV : x;                           \
        int   ni = gt ? xi : TI;                          \
        int   ci = gt ? TI : xi;                          \
        TV = nv; x = cv; TI = ni; xi = ci;                \
    }

#define INSERT_ELEM(X, XI)                                \
    {                                                     \
        float x = (X); int xi = (XI);                     \
        INSERT_STAGE(tv0, ti0)                            \
        INSERT_STAGE(tv1, ti1)                            \
        INSERT_STAGE(tv2, ti2)                            \
        INSERT_STAGE(tv3, ti3)                            \
        INSERT_STAGE(tv4, ti4)                            \
        INSERT_STAGE(tv5, ti5)                            \
        INSERT_STAGE(tv6, ti6)                            \
        INSERT_STAGE(tv7, ti7)                            \
        rm = fmaxf(rm, x);                                \
    }

#define INSERT_CHUNK(D, CI)                               \
    INSERT_ELEM((D).x, (CI) * 4 + 0)                      \
    INSERT_ELEM((D).y, (CI) * 4 + 1)                      \
    INSERT_ELEM((D).z, (CI) * 4 + 2)                      \
    INSERT_ELEM((D).w, (CI) * 4 + 3)

    // ---- 4 phases: stage 4 chunks (coalesced) -> transpose via LDS ->
    // insert 16 elements. No prefetch arrays: TLP hides HBM latency. ----
    #pragma unroll
    for (int p = 0; p < NPH; ++p) {
        #pragma unroll
        for (int i = 0; i < CPP; ++i) {
            int j = i * RPW + lane;
            int r = j >> 2, c = j & 3;          // r: 0..63, c: 0..3
            size_t g = waveBase4 + (size_t)r * (NEXP / 4) + p * CPP + c;
            if (g < totalChunks) {
                float4 v = src[g];
                dst[g] = v;                      // passthrough copy (cached:
                                                 // phases merge into full lines in L2)
                wtile[c * RPW + r] = v;
            }
        }
        // read my row's 4 chunks for this phase (same-wave DS is in-order;
        // WAR vs next phase's writes is safe for the same reason)
        float4 dA = wtile[0 * RPW + lane];
        float4 dB = wtile[1 * RPW + lane];
        float4 dC = wtile[2 * RPW + lane];
        float4 dD = wtile[3 * RPW + lane];
        INSERT_CHUNK(dA, p * 4 + 0)
        INSERT_CHUNK(dB, p * 4 + 1)
        INSERT_CHUNK(dC, p * 4 + 2)
        INSERT_CHUNK(dD, p * 4 + 3)
    }

    const int row = rowBase + lane;
    if (row >= nrows) return;

    // ---- tie screen: fp32 softmax can only collapse logits whose gap is
    // < ~2 ulp of (l - max); screen at 1e-6 covers all pairs that involve
    // a selected element (7 in-top gaps + the 8/9 boundary via rm). ----
    const float T = 1e-6f;
    bool tie = ((tv0 - tv1) <= T) | ((tv1 - tv2) <= T) | ((tv2 - tv3) <= T) |
               ((tv3 - tv4) <= T) | ((tv4 - tv5) <= T) | ((tv5 - tv6) <= T) |
               ((tv6 - tv7) <= T) | ((tv7 - rm)  <= T);

    float ce0, ce1, ce2, ce3, ce4, ce5, ce6, ce7;
    int   o0, o1, o2, o3, o4, o5, o6, o7;

    if (__builtin_expect(!tie, 1)) {
        // fast path: no representable score tie possible
        ce0 = 1.0f;
        ce1 = __expf(tv1 - tv0); ce2 = __expf(tv2 - tv0);
        ce3 = __expf(tv3 - tv0); ce4 = __expf(tv4 - tv0);
        ce5 = __expf(tv5 - tv0); ce6 = __expf(tv6 - tv0);
        ce7 = __expf(tv7 - tv0);
        o0 = ti0; o1 = ti1; o2 = ti2; o3 = ti3;
        o4 = ti4; o5 = ti5; o6 = ti6; o7 = ti7;
    } else {
        // exact path (rare, exec-masked): re-read the row from global and
        // redo depth-10 selection + correctly-rounded-exp tie semantics.
        const float* rowp = logits + (size_t)row * NEXP;
        float sv0 = -INFINITY, sv1 = -INFINITY, sv2 = -INFINITY, sv3 = -INFINITY;
        float sv4 = -INFINITY, sv5 = -INFINITY, sv6 = -INFINITY, sv7 = -INFINITY;
        float sv8 = -INFINITY, sv9 = -INFINITY;
        int   si0 = 0, si1 = 0, si2 = 0, si3 = 0, si4 = 0;
        int   si5 = 0, si6 = 0, si7 = 0, si8 = 0, si9 = 0;

#define SLOW_STAGE(TV, TI)                                \
    {                                                     \
        bool gt = (x > TV);                               \
        float nv = gt ? x  : TV;                          \
        float cv = gt ? TV : x;                           \
        int   ni = gt ? xi : TI;                          \
        int   ci = gt ? TI : xi;                          \
        TV = nv; x = cv; TI = ni; xi = ci;                \
    }

        #pragma unroll 1
        for (int e = 0; e < NEXP; ++e) {
            float x = rowp[e]; int xi = e;
            SLOW_STAGE(sv0, si0)
            SLOW_STAGE(sv1, si1)
            SLOW_STAGE(sv2, si2)
            SLOW_STAGE(sv3, si3)
            SLOW_STAGE(sv4, si4)
            SLOW_STAGE(sv5, si5)
            SLOW_STAGE(sv6, si6)
            SLOW_STAGE(sv7, si7)
            SLOW_STAGE(sv8, si8)
            SLOW_STAGE(sv9, si9)
        }

        double m = (double)sv0;
        float s0 = (float)exp((double)sv0 - m);
        float s1 = (float)exp((double)sv1 - m);
        float s2 = (float)exp((double)sv2 - m);
        float s3 = (float)exp((double)sv3 - m);
        float s4 = (float)exp((double)sv4 - m);
        float s5 = (float)exp((double)sv5 - m);
        float s6 = (float)exp((double)sv6 - m);
        float s7 = (float)exp((double)sv7 - m);
        float s8 = (float)exp((double)sv8 - m);
        float s9 = (float)exp((double)sv9 - m);

#define TIESWAP(CA, IA, CB, IB)                           \
    {                                                     \
        bool sw = (CA == CB) && (IA > IB);                \
        int tt = IA;                                      \
        IA = sw ? IB : IA;                                \
        IB = sw ? tt : IB;                                \
    }
#define TIEPASS                                           \
    TIESWAP(s0, si0, s1, si1)                             \
    TIESWAP(s1, si1, s2, si2)                             \
    TIESWAP(s2, si2, s3, si3)                             \
    TIESWAP(s3, si3, s4, si4)                             \
    TIESWAP(s4, si4, s5, si5)                             \
    TIESWAP(s5, si5, s6, si6)                             \
    TIESWAP(s6, si6, s7, si7)                             \
    TIESWAP(s7, si7, s8, si8)                             \
    TIESWAP(s8, si8, s9, si9)

        TIEPASS
        TIEPASS
        TIEPASS
        TIEPASS

        ce0 = s0; ce1 = s1; ce2 = s2; ce3 = s3;
        ce4 = s4; ce5 = s5; ce6 = s6; ce7 = s7;
        o0 = si0; o1 = si1; o2 = si2; o3 = si3;
        o4 = si4; o5 = si5; o6 = si6; o7 = si7;
    }

    float s = ((ce0 + ce1) + (ce2 + ce3)) + ((ce4 + ce5) + (ce6 + ce7));
    float r = 1.0f / s;

    floatx4 w0 = { ce0 * r, ce1 * r, ce2 * r, ce3 * r };
    floatx4 w1 = { ce4 * r, ce5 * r, ce6 * r, ce7 * r };
    floatx4 i0 = { (float)o0, (float)o1, (float)o2, (float)o3 };
    floatx4 i1 = { (float)o4, (float)o5, (float)o6, (float)o7 };

    // streamed outputs: nontemporal, frees L2 for the staged input combs
    floatx4* __restrict__ wp = (floatx4*)(w_out + (size_t)row * TOPK);
    __builtin_nontemporal_store(w0, &wp[0]);
    __builtin_nontemporal_store(w1, &wp[1]);
    floatx4* __restrict__ ip = (floatx4*)(id_out + (size_t)row * TOPK);
    __builtin_nontemporal_store(i0, &ip[0]);
    __builtin_nontemporal_store(i1, &ip[1]);
}

extern "C" void kernel_launch(void* const* d_in, const int* in_sizes, int n_in,
                              void* d_out, int out_size, void* d_ws, size_t ws_size,
                              hipStream_t stream) {
    const float* logits = (const float*)d_in[0];
    int nrows = in_sizes[0] / NEXP;

    float* out    = (float*)d_out;
    float* w_out  = out;
    float* id_out = out + (size_t)nrows * TOPK;
    float* l_out  = out + (size_t)nrows * 2 * TOPK;

    int threads = WPB * RPW;                        // 256
    int blocks = (nrows + (WPB * RPW) - 1) / (WPB * RPW);
    topk_router_kernel<<<blocks, threads, 0, stream>>>(logits, w_out, id_out, l_out, nrows);
}

// Round 10
// 144.052 us; speedup vs baseline: 2.0323x; 2.0323x over previous
//
#include <hip/hip_runtime.h>
#include <hip/hip_bf16.h>
#include <math.h>

#define NEXP 64
#define TOPK 8

// 4 lanes per row, 16 rows per wave, 4 independent waves per block (no
// barriers, no LDS). Cross-lane merge via __shfl_xor masks 1/2 (intra-quad
// -> DPP). Each lane: top-8 of its 16 contiguous elems, then 2 butterfly
// merge levels; all 4 lanes of a row end with the identical merged top-8.
__global__ __launch_bounds__(256) void topk_router_kernel(
    const float* __restrict__ logits,
    float* __restrict__ w_out,      // [N,8] weights
    float* __restrict__ id_out,     // [N,8] ids stored as float values
    float* __restrict__ l_out,      // [N,64] passthrough copy
    int nrows)
{
    const int lane = threadIdx.x & 63;
    const int wv   = threadIdx.x >> 6;
    const int q    = lane & 3;          // quarter of the row this lane owns
    const int rloc = lane >> 2;         // row within wave 0..15
    const int row  = (blockIdx.x * 4 + wv) * 16 + rloc;
    if (row >= nrows) return;           // whole 4-lane groups exit together

    const float4* __restrict__ src = (const float4*)logits + (size_t)row * (NEXP / 4) + q * 4;
    float4* __restrict__ dst       = (float4*)l_out  + (size_t)row * (NEXP / 4) + q * 4;

    // 64B contiguous per lane; the wave's 4 loads cover a contiguous 4KB
    // block (each 128B line fully consumed across the 4 instrs, L1-held).
    float4 a0 = src[0], a1 = src[1], a2 = src[2], a3 = src[3];
    dst[0] = a0; dst[1] = a1; dst[2] = a2; dst[3] = a3;   // lines are L2-hot

    // ---- per-lane sorted top-8 (desc, stable) of my 16 elems + rm ----
    float v0 = -INFINITY, v1 = -INFINITY, v2 = -INFINITY, v3 = -INFINITY;
    float v4 = -INFINITY, v5 = -INFINITY, v6 = -INFINITY, v7 = -INFINITY;
    float rm = -INFINITY;
    int   i0 = 0, i1 = 0, i2 = 0, i3 = 0, i4 = 0, i5 = 0, i6 = 0, i7 = 0;

#define INSERT_STAGE(TV, TI)                              \
    {                                                     \
        bool gt = (x > TV);                               \
        float nv = gt ? x  : TV;                          \
        float cv = gt ? TV : x;                           \
        int   ni = gt ? xi : TI;                          \
        int   ci = gt ? TI : xi;                          \
        TV = nv; x = cv; TI = ni; xi = ci;                \
    }

#define INSERT_ELEM(X, XI)                                \
    {                                                     \
        float x = (X); int xi = (XI);                     \
        INSERT_STAGE(v0, i0)                              \
        INSERT_STAGE(v1, i1)                              \
        INSERT_STAGE(v2, i2)                              \
        INSERT_STAGE(v3, i3)                              \
        INSERT_STAGE(v4, i4)                              \
        INSERT_STAGE(v5, i5)                              \
        INSERT_STAGE(v6, i6)                              \
        INSERT_STAGE(v7, i7)                              \
        rm = fmaxf(rm, x);                                \
    }

#define INSERT_CHUNK(D, BASE)                             \
    INSERT_ELEM((D).x, (BASE) + 0)                        \
    INSERT_ELEM((D).y, (BASE) + 1)                        \
    INSERT_ELEM((D).z, (BASE) + 2)                        \
    INSERT_ELEM((D).w, (BASE) + 3)

    INSERT_CHUNK(a0, q * 16 + 0)
    INSERT_CHUNK(a1, q * 16 + 4)
    INSERT_CHUNK(a2, q * 16 + 8)
    INSERT_CHUNK(a3, q * 16 + 12)

    // ---- butterfly merge of sorted-8 lists across lanes (masks 1, 2) ----
    // top-8 of two desc lists: L[k] = max(A[k], B[7-k]) (bitonic), then
    // 3-stage bitonic sort-8. H-side max feeds rm (max of all rejected).
#define CE(A, IA, B, IB)                                  \
    {                                                     \
        bool s_ = (B > A);                                \
        float tv_ = A; A = s_ ? B : A; B = s_ ? tv_ : B;  \
        int ti_ = IA; IA = s_ ? IB : IA; IB = s_ ? ti_ : IB; \
    }

#define MERGE_LEVEL(MASK)                                                   \
    {                                                                       \
        float b0 = __shfl_xor(v0, MASK), b1 = __shfl_xor(v1, MASK);         \
        float b2 = __shfl_xor(v2, MASK), b3 = __shfl_xor(v3, MASK);         \
        float b4 = __shfl_xor(v4, MASK), b5 = __shfl_xor(v5, MASK);         \
        float b6 = __shfl_xor(v6, MASK), b7 = __shfl_xor(v7, MASK);         \
        int   j0 = __shfl_xor(i0, MASK), j1 = __shfl_xor(i1, MASK);         \
        int   j2 = __shfl_xor(i2, MASK), j3 = __shfl_xor(i3, MASK);         \
        int   j4 = __shfl_xor(i4, MASK), j5 = __shfl_xor(i5, MASK);         \
        int   j6 = __shfl_xor(i6, MASK), j7 = __shfl_xor(i7, MASK);         \
        float pr = __shfl_xor(rm, MASK);                                    \
        float h = fmaxf(rm, pr);                                            \
        bool t_; float hv_;                                                 \
        t_ = (v0 >= b7); hv_ = t_ ? b7 : v0; v0 = t_ ? v0 : b7; i0 = t_ ? i0 : j7; h = fmaxf(h, hv_); \
        t_ = (v1 >= b6); hv_ = t_ ? b6 : v1; v1 = t_ ? v1 : b6; i1 = t_ ? i1 : j6; h = fmaxf(h, hv_); \
        t_ = (v2 >= b5); hv_ = t_ ? b5 : v2; v2 = t_ ? v2 : b5; i2 = t_ ? i2 : j5; h = fmaxf(h, hv_); \
        t_ = (v3 >= b4); hv_ = t_ ? b4 : v3; v3 = t_ ? v3 : b4; i3 = t_ ? i3 : j4; h = fmaxf(h, hv_); \
        t_ = (v4 >= b3); hv_ = t_ ? b3 : v4; v4 = t_ ? v4 : b3; i4 = t_ ? i4 : j3; h = fmaxf(h, hv_); \
        t_ = (v5 >= b2); hv_ = t_ ? b2 : v5; v5 = t_ ? v5 : b2; i5 = t_ ? i5 : j2; h = fmaxf(h, hv_); \
        t_ = (v6 >= b1); hv_ = t_ ? b1 : v6; v6 = t_ ? v6 : b1; i6 = t_ ? i6 : j1; h = fmaxf(h, hv_); \
        t_ = (v7 >= b0); hv_ = t_ ? b0 : v7; v7 = t_ ? v7 : b0; i7 = t_ ? i7 : j0; h = fmaxf(h, hv_); \
        CE(v0, i0, v4, i4) CE(v1, i1, v5, i5) CE(v2, i2, v6, i6) CE(v3, i3, v7, i7) \
        CE(v0, i0, v2, i2) CE(v1, i1, v3, i3) CE(v4, i4, v6, i6) CE(v5, i5, v7, i7) \
        CE(v0, i0, v1, i1) CE(v2, i2, v3, i3) CE(v4, i4, v5, i5) CE(v6, i6, v7, i7) \
        rm = h;                                                             \
    }

    MERGE_LEVEL(1)
    MERGE_LEVEL(2)

    // ---- tie screen: fp32 softmax can only collapse logits whose gap is
    // < ~2 ulp of (l - max); screen at 1e-6. If an equal pair straddles the
    // selection boundary then rm >= v7 -> gap <= 0 -> caught on all lanes.
    const float T = 1e-6f;
    bool tie = ((v0 - v1) <= T) | ((v1 - v2) <= T) | ((v2 - v3) <= T) |
               ((v3 - v4) <= T) | ((v4 - v5) <= T) | ((v5 - v6) <= T) |
               ((v6 - v7) <= T) | ((v7 - rm) <= T);

    float ce0, ce1, ce2, ce3, ce4, ce5, ce6, ce7;
    int   o0, o1, o2, o3, o4, o5, o6, o7;

    if (__builtin_expect(!tie, 1)) {
        // fast path: no representable score tie possible
        ce0 = 1.0f;
        ce1 = __expf(v1 - v0); ce2 = __expf(v2 - v0);
        ce3 = __expf(v3 - v0); ce4 = __expf(v4 - v0);
        ce5 = __expf(v5 - v0); ce6 = __expf(v6 - v0);
        ce7 = __expf(v7 - v0);
        o0 = i0; o1 = i1; o2 = i2; o3 = i3;
        o4 = i4; o5 = i5; o6 = i6; o7 = i7;
    } else {
        // exact path (rare, exec-masked, deterministic per row): re-read the
        // row, depth-10 stable selection + correctly-rounded-exp tie order.
        const float* rowp = logits + (size_t)row * NEXP;
        float sv0 = -INFINITY, sv1 = -INFINITY, sv2 = -INFINITY, sv3 = -INFINITY;
        float sv4 = -INFINITY, sv5 = -INFINITY, sv6 = -INFINITY, sv7 = -INFINITY;
        float sv8 = -INFINITY, sv9 = -INFINITY;
        int   si0 = 0, si1 = 0, si2 = 0, si3 = 0, si4 = 0;
        int   si5 = 0, si6 = 0, si7 = 0, si8 = 0, si9 = 0;

#define SLOW_STAGE(TV, TI)                                \
    {                                                     \
        bool gt = (x > TV);                               \
        float nv = gt ? x  : TV;                          \
        float cv = gt ? TV : x;                           \
        int   ni = gt ? xi : TI;                          \
        int   ci = gt ? TI : xi;                          \
        TV = nv; x = cv; TI = ni; xi = ci;                \
    }

        #pragma unroll 1
        for (int e = 0; e < NEXP; ++e) {
            float x = rowp[e]; int xi = e;
            SLOW_STAGE(sv0, si0)
            SLOW_STAGE(sv1, si1)
            SLOW_STAGE(sv2, si2)
            SLOW_STAGE(sv3, si3)
            SLOW_STAGE(sv4, si4)
            SLOW_STAGE(sv5, si5)
            SLOW_STAGE(sv6, si6)
            SLOW_STAGE(sv7, si7)
            SLOW_STAGE(sv8, si8)
            SLOW_STAGE(sv9, si9)
        }

        double m = (double)sv0;
        float s0 = (float)exp((double)sv0 - m);
        float s1 = (float)exp((double)sv1 - m);
        float s2 = (float)exp((double)sv2 - m);
        float s3 = (float)exp((double)sv3 - m);
        float s4 = (float)exp((double)sv4 - m);
        float s5 = (float)exp((double)sv5 - m);
        float s6 = (float)exp((double)sv6 - m);
        float s7 = (float)exp((double)sv7 - m);
        float s8 = (float)exp((double)sv8 - m);
        float s9 = (float)exp((double)sv9 - m);

#define TIESWAP(CA, IA, CB, IB)                           \
    {                                                     \
        bool sw = (CA == CB) && (IA > IB);                \
        int tt = IA;                                      \
        IA = sw ? IB : IA;                                \
        IB = sw ? tt : IB;                                \
    }
#define TIEPASS                                           \
    TIESWAP(s0, si0, s1, si1)                             \
    TIESWAP(s1, si1, s2, si2)                             \
    TIESWAP(s2, si2, s3, si3)                             \
    TIESWAP(s3, si3, s4, si4)                             \
    TIESWAP(s4, si4, s5, si5)                             \
    TIESWAP(s5, si5, s6, si6)                             \
    TIESWAP(s6, si6, s7, si7)                             \
    TIESWAP(s7, si7, s8, si8)                             \
    TIESWAP(s8, si8, s9, si9)

        TIEPASS
        TIEPASS
        TIEPASS
        TIEPASS

        ce0 = s0; ce1 = s1; ce2 = s2; ce3 = s3;
        ce4 = s4; ce5 = s5; ce6 = s6; ce7 = s7;
        o0 = si0; o1 = si1; o2 = si2; o3 = si3;
        o4 = si4; o5 = si5; o6 = si6; o7 = si7;
    }

    float s = ((ce0 + ce1) + (ce2 + ce3)) + ((ce4 + ce5) + (ce6 + ce7));
    float r = 1.0f / s;

    // ---- each lane stores ONE float4, selected by its quarter q:
    //   q=0 -> weights[0:4], q=1 -> weights[4:8], q=2 -> ids[0:4], q=3 -> ids[4:8]
    // wave footprint: 512B contiguous in w_out + 512B contiguous in id_out.
    const bool hi  = (q & 1);
    const bool typ = (q >> 1);      // 0 = weights, 1 = ids

    float4 outv;
    outv.x = typ ? (hi ? (float)o4 : (float)o0) : (hi ? ce4 * r : ce0 * r);
    outv.y = typ ? (hi ? (float)o5 : (float)o1) : (hi ? ce5 * r : ce1 * r);
    outv.z = typ ? (hi ? (float)o6 : (float)o2) : (hi ? ce6 * r : ce2 * r);
    outv.w = typ ? (hi ? (float)o7 : (float)o3) : (hi ? ce7 * r : ce3 * r);

    float* basep = typ ? id_out : w_out;
    float4* op = (float4*)(basep + (size_t)row * TOPK) + (hi ? 1 : 0);
    *op = outv;
}

extern "C" void kernel_launch(void* const* d_in, const int* in_sizes, int n_in,
                              void* d_out, int out_size, void* d_ws, size_t ws_size,
                              hipStream_t stream) {
    const float* logits = (const float*)d_in[0];
    int nrows = in_sizes[0] / NEXP;

    float* out    = (float*)d_out;
    float* w_out  = out;
    float* id_out = out + (size_t)nrows * TOPK;
    float* l_out  = out + (size_t)nrows * 2 * TOPK;

    // 64 rows per block (4 waves x 16 rows), 256 threads
    int blocks = (nrows + 63) / 64;
    topk_router_kernel<<<blocks, 256, 0, stream>>>(logits, w_out, id_out, l_out, nrows);
}